// Round 5
// baseline (6102.550 us; speedup 1.0000x reference)
//
#include <hip/hip_runtime.h>

#define DEVINL __device__ __forceinline__

namespace {
constexpr int B = 256, T = 128, F = 128, H = 512;
constexpr int NBLK = 128;        // 2 batch rows per block, no cross-block deps

// workspace layout in 4-byte words
constexpr size_t OFF_NUM   = 0;                        // [128] loss numerators
constexpr size_t OFF_DEN   = 128;                      // [128] denominators
constexpr size_t OFF_WGCC  = 256;                      // gate W cc|m f16x2 [128 k2][2048 col]
constexpr size_t OFF_WGH   = OFF_WGCC + 128 * 2048;    // gate W h-part i8x4 [128 k4][2048 col]
constexpr size_t OFF_FSCG  = OFF_WGH + 128 * 2048;     // [2048] col scale = max/16129
constexpr size_t OFF_HISTQ = OFF_FSCG + 2048;          // hist i8x4 [128 k4][128 f]
constexpr size_t OFF_FSCH  = OFF_HISTQ + 128 * 128;    // [128] col scale
constexpr size_t OFF_TD2   = OFF_FSCH + 128;           // td_h f16x2 [64 k2][512 j]
constexpr size_t OFF_FEAT2 = OFF_TD2 + 64 * 512;       // feat f16x2 [64 k2][128 f]
constexpr size_t OFF_WC2   = OFF_FEAT2 + 64 * 128;     // wc   f16x2 [128 k2][128 f]
constexpr size_t OFF_BSUM  = OFF_WC2 + 128 * 128;      // [2048] b_ih+b_hh gate-interleaved
constexpr size_t OFF_FDIAG = OFF_BSUM + 2048;          // [128] f16-rounded feat diag
constexpr size_t WS_WORDS  = OFF_FDIAG + 128;          // ~2.41 MB (<8.2 MB known-good)
}

typedef _Float16 h2_t __attribute__((ext_vector_type(2)));

DEVINL h2_t as_h2(unsigned u) { union { unsigned u; h2_t h; } c; c.u = u; return c.h; }
DEVINL unsigned pack2(float a, float b) {
  union { h2_t h; unsigned u; } c;
  c.h = h2_t{(_Float16)a, (_Float16)b};
  return c.u;
}

#if defined(__has_builtin)
#if __has_builtin(__builtin_amdgcn_fdot2)
#define HAVE_FDOT2 1
#endif
#if __has_builtin(__builtin_amdgcn_sdot4)
#define HAVE_SDOT4 1
#endif
#endif
#ifdef HAVE_FDOT2
DEVINL float fdot2(h2_t a, h2_t b, float c) { return __builtin_amdgcn_fdot2(a, b, c, false); }
#else
DEVINL float fdot2(h2_t a, h2_t b, float c) {
  return fmaf((float)a.x, (float)b.x, fmaf((float)a.y, (float)b.y, c));
}
#endif
#ifdef HAVE_SDOT4
DEVINL int sdot4(int a, int b, int c) { return __builtin_amdgcn_sdot4(a, b, c, false); }
#else
DEVINL int sdot4(int a, int b, int c) {
  return c + ((a << 24) >> 24) * ((b << 24) >> 24)
           + ((a << 16) >> 24) * ((b << 16) >> 24)
           + ((a << 8) >> 24) * ((b << 8) >> 24)
           + (a >> 24) * (b >> 24);
}
#endif

DEVINL float fast_sig(float x)  { return 1.f / (1.f + __expf(-x)); }
DEVINL float fast_tanh(float x) { return 1.f - 2.f / (1.f + __expf(2.f * x)); }

DEVINL float wave_sum(float v) {
#pragma unroll
  for (int s = 32; s; s >>= 1) v += __shfl_down(v, s, 64);
  return v;
}
DEVINL float wave_max(float v) {
#pragma unroll
  for (int s = 32; s; s >>= 1) v = fmaxf(v, __shfl_down(v, s, 64));
  return v;
}

// ---- prep: all f16 tables + biases ----
__global__ void prep_f16(const float* __restrict__ Wih, const float* __restrict__ td_h_W,
                         const float* __restrict__ feat_W, const float* __restrict__ wc_W,
                         const float* __restrict__ b_ih, const float* __restrict__ b_hh,
                         unsigned* __restrict__ wsu, float* __restrict__ wsf) {
  int idx = blockIdx.x * blockDim.x + threadIdx.x;
  if (idx < 262144) {                          // WGCC [k2][col], col = 4*unit+gate
    const int k2 = idx >> 11, col = idx & 2047, unit = col >> 2, g = col & 3;
    const int row = g * 512 + unit;
    wsu[OFF_WGCC + idx] = pack2(Wih[row * 256 + 2 * k2], Wih[row * 256 + 2 * k2 + 1]);
  } else if (idx < 294912) {                   // TD2 [64][512]
    const int i = idx - 262144, k2 = i >> 9, j = i & 511;
    wsu[OFF_TD2 + i] = pack2(td_h_W[j * 128 + 2 * k2], td_h_W[j * 128 + 2 * k2 + 1]);
  } else if (idx < 303104) {                   // FEAT2 [64][128]
    const int i = idx - 294912, k2 = i >> 7, f = i & 127;
    wsu[OFF_FEAT2 + i] = pack2(feat_W[f * 128 + 2 * k2], feat_W[f * 128 + 2 * k2 + 1]);
  } else if (idx < 319488) {                   // WC2 [128][128]
    const int i = idx - 303104, k2 = i >> 7, f = i & 127;
    wsu[OFF_WC2 + i] = pack2(wc_W[f * 256 + 2 * k2], wc_W[f * 256 + 2 * k2 + 1]);
  } else if (idx < 321536) {                   // BSUM [2048]
    const int i = idx - 319488, unit = i >> 2, g = i & 3;
    wsf[OFF_BSUM + i] = b_ih[g * 512 + unit] + b_hh[g * 512 + unit];
  } else if (idx < 321664) {                   // FDIAG [128]
    const int f = idx - 321536;
    wsf[OFF_FDIAG + f] = (float)(_Float16)feat_W[f * 129];
  }
}

// ---- prep: int8 per-column quant of W_hh gate columns [K=512] ----
__global__ void prep_quant_gates(const float* __restrict__ Whh,
                                 unsigned* __restrict__ wgh, float* __restrict__ fscg) {
  const int col = blockIdx.x;                  // 2048 cols = 4*unit+gate
  const int unit = col >> 2, g = col & 3;
  const float* src = Whh + (size_t)(g * 512 + unit) * 512;
  const int t = threadIdx.x;                   // 128 threads, 4 k each
  const float4 v = ((const float4*)src)[t];
  float mx = fmaxf(fmaxf(fabsf(v.x), fabsf(v.y)), fmaxf(fabsf(v.z), fabsf(v.w)));
  mx = wave_max(mx);
  __shared__ float wm[2];
  if ((t & 63) == 0) wm[t >> 6] = mx;
  __syncthreads();
  const float maxv = fmaxf(wm[0], wm[1]);
  const float s = (maxv > 0.f) ? 127.f / maxv : 0.f;
  const int q0 = __float2int_rn(v.x * s), q1 = __float2int_rn(v.y * s);
  const int q2 = __float2int_rn(v.z * s), q3 = __float2int_rn(v.w * s);
  wgh[t * 2048 + col] =
      (q0 & 0xFF) | ((q1 & 0xFF) << 8) | ((q2 & 0xFF) << 16) | ((q3 & 0xFF) << 24);
  if (t == 0) fscg[col] = maxv * (1.f / 16129.f);   // (max/127)/127
}

// ---- prep: int8 per-column quant of hist_W rows [K=512] ----
__global__ void prep_quant_hist(const float* __restrict__ histW,
                                unsigned* __restrict__ histq, float* __restrict__ fsch) {
  const int f = blockIdx.x;                    // 128 cols
  const float* src = histW + (size_t)f * 512;
  const int t = threadIdx.x;
  const float4 v = ((const float4*)src)[t];
  float mx = fmaxf(fmaxf(fabsf(v.x), fabsf(v.y)), fmaxf(fabsf(v.z), fabsf(v.w)));
  mx = wave_max(mx);
  __shared__ float wm[2];
  if ((t & 63) == 0) wm[t >> 6] = mx;
  __syncthreads();
  const float maxv = fmaxf(wm[0], wm[1]);
  const float s = (maxv > 0.f) ? 127.f / maxv : 0.f;
  const int q0 = __float2int_rn(v.x * s), q1 = __float2int_rn(v.y * s);
  const int q2 = __float2int_rn(v.z * s), q3 = __float2int_rn(v.w * s);
  histq[t * 128 + f] =
      (q0 & 0xFF) | ((q1 & 0xFF) << 8) | ((q2 & 0xFF) << 16) | ((q3 & 0xFF) << 24);
  if (t == 0) fsch[f] = maxv * (1.f / 16129.f);
}

// ---- main: 128 blocks x 1024 threads; 2 rows/block; h,c in LDS; no grid sync ----
__global__ void __launch_bounds__(1024) rits_batch(
    const float* __restrict__ x, const float* __restrict__ m, const float* __restrict__ d,
    const float* __restrict__ tx, const float* __restrict__ tmask,
    const float* __restrict__ td_h_b, const float* __restrict__ td_x_W,
    const float* __restrict__ td_x_b, const float* __restrict__ hist_b,
    const float* __restrict__ feat_b, const float* __restrict__ wc_b,
    const unsigned* __restrict__ wsu, const float* __restrict__ wsf,
    float* __restrict__ num, float* __restrict__ den, float* __restrict__ out)
{
  const int tid = threadIdx.x;
  const int row0 = blockIdx.x * 2;
  const int unit = tid >> 1, r1 = tid & 1;     // phase C / I mapping (pairs share W lines)

  __shared__ float h_ls[1024], c_ls[1024];     // [r][512]
  __shared__ unsigned act[256];                // [r][128]: cc pairs 0..63 | m pairs 64..127
  __shared__ int hq[256];                      // [r][128]: decayed h as i8x4
  __shared__ unsigned d2[128];                 // [r][64] d f16 pairs
  __shared__ unsigned xc2[128];                // [r][64] x_c f16 pairs
  __shared__ unsigned gxm2[256];               // [r][128]: gx pairs 0..63 | m pairs 64..127
  __shared__ float xrow[256], mrow[256], drow[256], txrow[256], evrow[256];
  __shared__ float xh_ls[256], xc_ls[256];
  __shared__ int   partI[1024];
  __shared__ float partF[1024], partA[1024];
  __shared__ float redA[4], redB[4];

  // per-thread persistent constants
  const float4 bs  = *(const float4*)(wsf + OFF_BSUM + 4 * unit);
  const float4 fsc = *(const float4*)(wsf + OFF_FSCG + 4 * unit);
  const float tdb = td_h_b[unit];
  float hb = 0, fb = 0, wb = 0, fd = 0, dxw = 0, dxb = 0, fsch_f = 0;
  if (tid < 256) {
    const int f = tid & 127;
    hb = hist_b[f]; fb = feat_b[f]; wb = wc_b[f];
    fd = wsf[OFF_FDIAG + f]; dxw = td_x_W[f * 129]; dxb = td_x_b[f];
    fsch_f = wsf[OFF_FSCH + f];
  }
  h_ls[tid] = 0.f; c_ls[tid] = 0.f;
  __syncthreads();

  for (int t = 0; t < T; ++t) {
    // ---- A: load input rows + pack d2 + pack m pairs (1536 items) ----
    for (int i = tid; i < 1536; i += 1024) {
      if (i < 1280) {
        const int a = i >> 8, j = i & 255, r = j >> 7, f = j & 127;
        const int idx = ((row0 + r) * T + t) * F + f;
        if      (a == 0) xrow[j]  = x[idx];
        else if (a == 1) mrow[j]  = m[idx];
        else if (a == 2) drow[j]  = d[idx];
        else if (a == 3) txrow[j] = tx[idx];
        else             evrow[j] = tmask[idx];
      } else if (i < 1408) {
        const int j = i - 1280, r = j >> 6, k2 = j & 63;
        const int base = ((row0 + r) * T + t) * F;
        d2[j] = pack2(d[base + 2 * k2], d[base + 2 * k2 + 1]);
      } else {
        const int j = i - 1408, r = j >> 6, q = j & 63;
        const int base = ((row0 + r) * T + t) * F;
        const unsigned w = pack2(m[base + 2 * q], m[base + 2 * q + 1]);
        act[r * 128 + 64 + q]  = w;
        gxm2[r * 128 + 64 + q] = w;
      }
    }
    __syncthreads();

    // ---- C: gamma_h dot (K=64 pairs), decay h, pack h -> i8x4 ----
    {
      float g = tdb;
#pragma unroll 8
      for (int k2 = 0; k2 < 64; ++k2)
        g = fdot2(as_h2(wsu[OFF_TD2 + (k2 << 9) + unit]), as_h2(d2[r1 * 64 + k2]), g);
      const float hn = h_ls[r1 * 512 + unit] * __expf(-fmaxf(g, 0.f));
      h_ls[r1 * 512 + unit] = hn;
      int q = __float2int_rn(hn * 127.f);
      const int q2 = __shfl_down(q, 2, 64), q4 = __shfl_down(q, 4, 64), q6 = __shfl_down(q, 6, 64);
      if (((tid >> 1) & 3) == 0)
        hq[r1 * 128 + (unit >> 2)] =
            (q & 0xFF) | ((q2 & 0xFF) << 8) | ((q4 & 0xFF) << 16) | ((q6 & 0xFF) << 24);
    }
    __syncthreads();

    // ---- E: x_hist partials, i8 dot4, K split 4 ways ----
    {
      const int kq = tid >> 8, j = tid & 255, r = j >> 7, f = j & 127;
      int isum = 0;
#pragma unroll 8
      for (int k = 0; k < 32; ++k) {
        const int kk = kq * 32 + k;
        isum = sdot4((int)wsu[OFF_HISTQ + (kk << 7) + f], hq[r * 128 + kk], isum);
      }
      partI[tid] = isum;
    }
    __syncthreads();

    // ---- E': reduce x_hist; gamma_x; x_c; pack xc2/gx pairs via shfl ----
    if (tid < 256) {
      const int r = tid >> 7, f = tid & 127;
      const int isum = partI[tid] + partI[tid + 256] + partI[tid + 512] + partI[tid + 768];
      const float xh = fmaf((float)isum, fsch_f, hb);
      xh_ls[tid] = xh;
      const float gx = __expf(-fmaxf(fmaf(drow[tid], dxw, dxb), 0.f));
      const float mv = mrow[tid];
      const float xc = mv * xrow[tid] + (1.f - mv) * xh;
      xc_ls[tid] = xc;
      const float xcs = __shfl_down(xc, 1, 64);
      const float gxs = __shfl_down(gx, 1, 64);
      if (!(f & 1)) {
        xc2[r * 64 + (f >> 1)]   = pack2(xc, xcs);
        gxm2[r * 128 + (f >> 1)] = pack2(gx, gxs);
      }
    }
    __syncthreads();

    // ---- G: feat partials (K=64 pairs) + alpha partials (K=128 pairs) ----
    {
      const int kq = tid >> 8, j = tid & 255, r = j >> 7, f = j & 127;
      float fs = 0.f;
#pragma unroll 8
      for (int k = 0; k < 16; ++k) {
        const int kk = kq * 16 + k;
        fs = fdot2(as_h2(wsu[OFF_FEAT2 + (kk << 7) + f]), as_h2(xc2[r * 64 + kk]), fs);
      }
      partF[tid] = fs;
      float as = 0.f;
#pragma unroll 8
      for (int k = 0; k < 32; ++k) {
        const int kk = kq * 32 + k;
        as = fdot2(as_h2(wsu[OFF_WC2 + (kk << 7) + f]), as_h2(gxm2[r * 128 + kk]), as);
      }
      partA[tid] = as;
    }
    __syncthreads();

    // ---- G': z_h, alpha, c_h, c_c, out write, loss partials, pack cc ----
    if (tid < 256) {
      const int r = tid >> 7, f = tid & 127;
      float z = partF[tid] + partF[tid + 256] + partF[tid + 512] + partF[tid + 768] + fb;
      z -= xc_ls[tid] * fd;                    // remove diagonal
      const float aa = partA[tid] + partA[tid + 256] + partA[tid + 512] + partA[tid + 768] + wb;
      const float al = fast_sig(aa);
      const float xh = xh_ls[tid];
      const float ch = al * z + (1.f - al) * xh;
      const float mv = mrow[tid];
      const float cc = mv * xrow[tid] + (1.f - mv) * ch;
      out[((row0 + r) * T + t) * F + f] = cc;
      const float ev = evrow[tid], tg = txrow[tid];
      const float e1 = xh - tg, e2 = z - tg, e3 = ch - tg;
      const float s1 = wave_sum(ev * (e1 * e1 + e2 * e2 + e3 * e3));
      const float s2 = wave_sum(ev);
      if ((tid & 63) == 0) { redA[tid >> 6] = s1; redB[tid >> 6] = s2; }
      const float ccs = __shfl_down(cc, 1, 64);
      if (!(f & 1)) act[r * 128 + (f >> 1)] = pack2(cc, ccs);
    }
    __syncthreads();

    // ---- I: gates (cc|m f16 K=128 pairs + h i8 K=128 words), LSTM update ----
    {
      if (tid == 1023) {
        atomicAdd(&num[t], redA[0] + redA[1] + redA[2] + redA[3]);
        atomicAdd(&den[t], redB[0] + redB[1] + redB[2] + redB[3]);
      }
      const unsigned* wcc = wsu + OFF_WGCC + 4 * unit;
      const unsigned* wh  = wsu + OFF_WGH  + 4 * unit;
      float ai = bs.x, af = bs.y, ag = bs.z, ao = bs.w;
#pragma unroll 8
      for (int k2 = 0; k2 < 128; ++k2) {
        const uint4 w = *(const uint4*)(wcc + (k2 << 11));
        const h2_t a = as_h2(act[r1 * 128 + k2]);
        ai = fdot2(as_h2(w.x), a, ai); af = fdot2(as_h2(w.y), a, af);
        ag = fdot2(as_h2(w.z), a, ag); ao = fdot2(as_h2(w.w), a, ao);
      }
      int ii = 0, jf = 0, jg = 0, jo = 0;
#pragma unroll 8
      for (int k4 = 0; k4 < 128; ++k4) {
        const uint4 w = *(const uint4*)(wh + (k4 << 11));
        const int a = hq[r1 * 128 + k4];
        ii = sdot4((int)w.x, a, ii); jf = sdot4((int)w.y, a, jf);
        jg = sdot4((int)w.z, a, jg); jo = sdot4((int)w.w, a, jo);
      }
      ai = fmaf((float)ii, fsc.x, ai); af = fmaf((float)jf, fsc.y, af);
      ag = fmaf((float)jg, fsc.z, ag); ao = fmaf((float)jo, fsc.w, ao);
      const float ig = fast_sig(ai), fg = fast_sig(af);
      const float gg = fast_tanh(ag), og = fast_sig(ao);
      const float cn = fg * c_ls[r1 * 512 + unit] + ig * gg;
      c_ls[r1 * 512 + unit] = cn;
      h_ls[r1 * 512 + unit] = og * fast_tanh(cn);
    }
    __syncthreads();
  }
}

__global__ void finalize(const float* __restrict__ num, const float* __restrict__ den,
                         float* __restrict__ out) {
  __shared__ float red[2];
  const int t = threadIdx.x;     // 128 threads
  float v = num[t] / (den[t] + 1e-8f);
  v = wave_sum(v);
  if ((t & 63) == 0) red[t >> 6] = v;
  __syncthreads();
  if (t == 0) out[(size_t)B * T * F] = (red[0] + red[1]) / (float)T;
}

extern "C" void kernel_launch(void* const* d_in, const int* in_sizes, int n_in,
                              void* d_out, int out_size, void* d_ws, size_t ws_size,
                              hipStream_t stream) {
  const float* x      = (const float*)d_in[0];
  const float* m      = (const float*)d_in[1];
  const float* d      = (const float*)d_in[2];
  const float* tx     = (const float*)d_in[3];
  const float* tmask  = (const float*)d_in[4];
  const float* td_h_W = (const float*)d_in[5];
  const float* td_h_b = (const float*)d_in[6];
  const float* td_x_W = (const float*)d_in[7];
  const float* td_x_b = (const float*)d_in[8];
  const float* hist_W = (const float*)d_in[9];
  const float* hist_b = (const float*)d_in[10];
  const float* feat_W = (const float*)d_in[11];
  const float* feat_b = (const float*)d_in[12];
  const float* wc_W   = (const float*)d_in[13];
  const float* wc_b   = (const float*)d_in[14];
  const float* W_ih   = (const float*)d_in[15];
  const float* W_hh   = (const float*)d_in[16];
  const float* b_ih   = (const float*)d_in[17];
  const float* b_hh   = (const float*)d_in[18];

  float*    wsf = (float*)d_ws;
  unsigned* wsu = (unsigned*)d_ws;
  float*    out = (float*)d_out;

  if (ws_size < WS_WORDS * 4) return;   // OOB tripwire (2.4 MB < 8.2 MB known-good)

  hipMemsetAsync(d_ws, 0, 256 * sizeof(float), stream);   // num/den
  prep_f16<<<dim3((321664 + 255) / 256), dim3(256), 0, stream>>>(
      W_ih, td_h_W, feat_W, wc_W, b_ih, b_hh, wsu, wsf);
  prep_quant_gates<<<dim3(2048), dim3(128), 0, stream>>>(
      W_hh, wsu + OFF_WGH, wsf + OFF_FSCG);
  prep_quant_hist<<<dim3(128), dim3(128), 0, stream>>>(
      hist_W, wsu + OFF_HISTQ, wsf + OFF_FSCH);
  rits_batch<<<dim3(NBLK), dim3(1024), 0, stream>>>(
      x, m, d, tx, tmask, td_h_b, td_x_W, td_x_b, hist_b, feat_b, wc_b,
      wsu, wsf, wsf + OFF_NUM, wsf + OFF_DEN, out);
  finalize<<<dim3(1), dim3(128), 0, stream>>>(wsf + OFF_NUM, wsf + OFF_DEN, out);
}

// Round 6
// 4250.153 us; speedup vs baseline: 1.4358x; 1.4358x over previous
//
#include <hip/hip_runtime.h>

#define DEVINL __device__ __forceinline__

namespace {
constexpr int B = 256, T = 128, F = 128, H = 512;
constexpr int NBLK = 128;        // 2 batch rows per block, no cross-block deps

// workspace layout in 4-byte words
constexpr size_t OFF_NUM    = 0;                         // [128] loss numerators
constexpr size_t OFF_DEN    = 128;                       // [128] denominators
constexpr size_t OFF_WQCC   = 256;                       // gates cc|m i8x4 [64 k4][2048 col]
constexpr size_t OFF_WQH    = OFF_WQCC + 64 * 2048;      // gates h    i8x4 [128 k4][2048 col]
constexpr size_t OFF_FSCC   = OFF_WQH + 128 * 2048;      // [2048] colmax/(127*15.875)
constexpr size_t OFF_FSCHG  = OFF_FSCC + 2048;           // [2048] colmax/16129
constexpr size_t OFF_HISTQ  = OFF_FSCHG + 2048;          // hist i8x4 [128 k4][128 f]
constexpr size_t OFF_FSCH   = OFF_HISTQ + 128 * 128;     // [128] colmax/16129
constexpr size_t OFF_TD2    = OFF_FSCH + 128;            // td_h f16x2 [64 k2][512 j]
constexpr size_t OFF_FEAT2  = OFF_TD2 + 64 * 512;        // feat f16x2 [64 k2][128 f]
constexpr size_t OFF_WC2    = OFF_FEAT2 + 64 * 128;      // wc   f16x2 [128 k2][128 f]
constexpr size_t OFF_BSUM   = OFF_WC2 + 128 * 128;       // [2048] b_ih+b_hh gate-interleaved
constexpr size_t OFF_FDIAG  = OFF_BSUM + 2048;           // [128] f16-rounded feat diag
constexpr size_t WS_WORDS   = OFF_FDIAG + 128;           // ~1.81 MB (<8.2 MB known-good)

constexpr float ACT_S  = 15.875f;                // cc|m activation scale (clamp +-8)
constexpr float DEQ_CC = 1.f / (127.f * 15.875f);
constexpr float DEQ_H  = 1.f / (127.f * 127.f);
}

typedef _Float16 h2_t __attribute__((ext_vector_type(2)));

DEVINL h2_t as_h2(unsigned u) { union { unsigned u; h2_t h; } c; c.u = u; return c.h; }
DEVINL unsigned pack2(float a, float b) {
  union { h2_t h; unsigned u; } c;
  c.h = h2_t{(_Float16)a, (_Float16)b};
  return c.u;
}

#if defined(__has_builtin)
#if __has_builtin(__builtin_amdgcn_fdot2)
#define HAVE_FDOT2 1
#endif
#if __has_builtin(__builtin_amdgcn_sdot4)
#define HAVE_SDOT4 1
#endif
#endif
#ifdef HAVE_FDOT2
DEVINL float fdot2(h2_t a, h2_t b, float c) { return __builtin_amdgcn_fdot2(a, b, c, false); }
#else
DEVINL float fdot2(h2_t a, h2_t b, float c) {
  return fmaf((float)a.x, (float)b.x, fmaf((float)a.y, (float)b.y, c));
}
#endif
#ifdef HAVE_SDOT4
DEVINL int sdot4(int a, int b, int c) { return __builtin_amdgcn_sdot4(a, b, c, false); }
#else
DEVINL int sdot4(int a, int b, int c) {
  return c + ((a << 24) >> 24) * ((b << 24) >> 24)
           + ((a << 16) >> 24) * ((b << 16) >> 24)
           + ((a << 8) >> 24) * ((b << 8) >> 24)
           + (a >> 24) * (b >> 24);
}
#endif

DEVINL float fast_sig(float x)  { return 1.f / (1.f + __expf(-x)); }
DEVINL float fast_tanh(float x) { return 1.f - 2.f / (1.f + __expf(2.f * x)); }

DEVINL float wave_sum(float v) {
#pragma unroll
  for (int s = 32; s; s >>= 1) v += __shfl_down(v, s, 64);
  return v;
}
DEVINL float wave_max(float v) {
#pragma unroll
  for (int s = 32; s; s >>= 1) v = fmaxf(v, __shfl_down(v, s, 64));
  return v;
}

// ---- prep: f16 tables + biases (TD2, FEAT2, WC2, BSUM, FDIAG) ----
__global__ void prep_f16(const float* __restrict__ td_h_W, const float* __restrict__ feat_W,
                         const float* __restrict__ wc_W, const float* __restrict__ b_ih,
                         const float* __restrict__ b_hh,
                         unsigned* __restrict__ wsu, float* __restrict__ wsf) {
  int idx = blockIdx.x * blockDim.x + threadIdx.x;
  if (idx < 32768) {                           // TD2 [64][512]
    const int k2 = idx >> 9, j = idx & 511;
    wsu[OFF_TD2 + idx] = pack2(td_h_W[j * 128 + 2 * k2], td_h_W[j * 128 + 2 * k2 + 1]);
  } else if (idx < 40960) {                    // FEAT2 [64][128]
    const int i = idx - 32768, k2 = i >> 7, f = i & 127;
    wsu[OFF_FEAT2 + i] = pack2(feat_W[f * 128 + 2 * k2], feat_W[f * 128 + 2 * k2 + 1]);
  } else if (idx < 57344) {                    // WC2 [128][128]
    const int i = idx - 40960, k2 = i >> 7, f = i & 127;
    wsu[OFF_WC2 + i] = pack2(wc_W[f * 256 + 2 * k2], wc_W[f * 256 + 2 * k2 + 1]);
  } else if (idx < 59392) {                    // BSUM [2048]
    const int i = idx - 57344, unit = i >> 2, g = i & 3;
    wsf[OFF_BSUM + i] = b_ih[g * 512 + unit] + b_hh[g * 512 + unit];
  } else if (idx < 59520) {                    // FDIAG [128]
    const int f = idx - 59392;
    wsf[OFF_FDIAG + f] = (float)(_Float16)feat_W[f * 129];
  }
}

// ---- prep: i8 quant of W_ih columns (K=256, cc|m part), per-column scale ----
__global__ void prep_quant_wih(const float* __restrict__ Wih,
                               unsigned* __restrict__ wq, float* __restrict__ fscc) {
  const int col = blockIdx.x;                  // 2048 = 4*unit+gate
  const int unit = col >> 2, g = col & 3;
  const float* src = Wih + (size_t)(g * 512 + unit) * 256;
  const int t = threadIdx.x;                   // 64 threads (one wave), 4 k each
  const float4 v = ((const float4*)src)[t];
  float mx = fmaxf(fmaxf(fabsf(v.x), fabsf(v.y)), fmaxf(fabsf(v.z), fabsf(v.w)));
  mx = wave_max(mx);
  mx = __shfl(mx, 0, 64);
  const float s = (mx > 0.f) ? 127.f / mx : 0.f;
  const int q0 = __float2int_rn(v.x * s), q1 = __float2int_rn(v.y * s);
  const int q2 = __float2int_rn(v.z * s), q3 = __float2int_rn(v.w * s);
  wq[t * 2048 + col] =
      (q0 & 0xFF) | ((q1 & 0xFF) << 8) | ((q2 & 0xFF) << 16) | ((q3 & 0xFF) << 24);
  if (t == 0) fscc[col] = mx * DEQ_CC;
}

// ---- prep: i8 quant of W_hh columns (K=512, h part) ----
__global__ void prep_quant_whh(const float* __restrict__ Whh,
                               unsigned* __restrict__ wq, float* __restrict__ fschg) {
  const int col = blockIdx.x;
  const int unit = col >> 2, g = col & 3;
  const float* src = Whh + (size_t)(g * 512 + unit) * 512;
  const int t = threadIdx.x;                   // 128 threads, 4 k each
  const float4 v = ((const float4*)src)[t];
  float mx = fmaxf(fmaxf(fabsf(v.x), fabsf(v.y)), fmaxf(fabsf(v.z), fabsf(v.w)));
  mx = wave_max(mx);
  __shared__ float wm[2];
  if ((t & 63) == 0) wm[t >> 6] = mx;
  __syncthreads();
  const float maxv = fmaxf(wm[0], wm[1]);
  const float s = (maxv > 0.f) ? 127.f / maxv : 0.f;
  const int q0 = __float2int_rn(v.x * s), q1 = __float2int_rn(v.y * s);
  const int q2 = __float2int_rn(v.z * s), q3 = __float2int_rn(v.w * s);
  wq[t * 2048 + col] =
      (q0 & 0xFF) | ((q1 & 0xFF) << 8) | ((q2 & 0xFF) << 16) | ((q3 & 0xFF) << 24);
  if (t == 0) fschg[col] = maxv * DEQ_H;
}

// ---- prep: i8 quant of hist_W rows (K=512) ----
__global__ void prep_quant_hist(const float* __restrict__ histW,
                                unsigned* __restrict__ histq, float* __restrict__ fsch) {
  const int f = blockIdx.x;                    // 128
  const float* src = histW + (size_t)f * 512;
  const int t = threadIdx.x;                   // 128 threads
  const float4 v = ((const float4*)src)[t];
  float mx = fmaxf(fmaxf(fabsf(v.x), fabsf(v.y)), fmaxf(fabsf(v.z), fabsf(v.w)));
  mx = wave_max(mx);
  __shared__ float wm[2];
  if ((t & 63) == 0) wm[t >> 6] = mx;
  __syncthreads();
  const float maxv = fmaxf(wm[0], wm[1]);
  const float s = (maxv > 0.f) ? 127.f / maxv : 0.f;
  const int q0 = __float2int_rn(v.x * s), q1 = __float2int_rn(v.y * s);
  const int q2 = __float2int_rn(v.z * s), q3 = __float2int_rn(v.w * s);
  histq[t * 128 + f] =
      (q0 & 0xFF) | ((q1 & 0xFF) << 8) | ((q2 & 0xFF) << 16) | ((q3 & 0xFF) << 24);
  if (t == 0) fsch[f] = maxv * DEQ_H;
}

// ---- main: 128 blocks x 512 threads (round-4 skeleton); 2 rows/block;
//      h,c in REGISTERS of thread=unit; all gate/hist weights int8 ----
__global__ void __launch_bounds__(512) rits_batch(
    const float* __restrict__ x, const float* __restrict__ m, const float* __restrict__ d,
    const float* __restrict__ tx, const float* __restrict__ tmask,
    const float* __restrict__ td_h_b, const float* __restrict__ td_x_W,
    const float* __restrict__ td_x_b, const float* __restrict__ hist_b,
    const float* __restrict__ feat_b, const float* __restrict__ wc_b,
    const unsigned* __restrict__ wsu, const float* __restrict__ wsf,
    float* __restrict__ num, float* __restrict__ den, float* __restrict__ out)
{
  const int tid = threadIdx.x;                 // = unit in phases C/I
  const int row0 = blockIdx.x * 2;

  __shared__ unsigned actq[2 * 64];            // [r][64 w]: cc i8 words 0..31 | m i8 32..63
  __shared__ int hq[2 * 128];                  // [r][128 w] decayed h i8 (scale 127)
  __shared__ unsigned d2[2 * 64];              // d f16 pairs
  __shared__ unsigned xc2[2 * 64];             // x_c f16 pairs
  __shared__ unsigned gxm2[2 * 128];           // [r]: gx pairs 0..63 | m pairs 64..127
  __shared__ float xrow[256], mrow[256], drow[256], txrow[256], evrow[256];
  __shared__ float xh_ls[256], xc_ls[256];
  __shared__ float redA[4], redB[4];

  // persistent per-thread constants (unit = tid)
  const float4 bs    = *(const float4*)(wsf + OFF_BSUM + 4 * tid);
  const float4 fscc4 = *(const float4*)(wsf + OFF_FSCC + 4 * tid);
  const float4 fsch4 = *(const float4*)(wsf + OFF_FSCHG + 4 * tid);
  const float tdb = td_h_b[tid];
  float hb = 0, fb = 0, wb = 0, fd = 0, dxw = 0, dxb = 0, fsch_f = 0;
  if (tid < 256) {
    const int f = tid & 127;
    hb = hist_b[f]; fb = feat_b[f]; wb = wc_b[f];
    fd = wsf[OFF_FDIAG + f]; dxw = td_x_W[f * 129]; dxb = td_x_b[f];
    fsch_f = wsf[OFF_FSCH + f];
  }
  float h0 = 0.f, h1 = 0.f, c0 = 0.f, c1 = 0.f;   // recurrent state in registers

  for (int t = 0; t < T; ++t) {
    // ---- A: input rows + d2 pairs + m f16 pairs + m i8 words (1600 items) ----
    for (int i = tid; i < 1600; i += 512) {
      if (i < 1280) {
        const int a = i >> 8, j = i & 255, r = j >> 7, f = j & 127;
        const int idx = ((row0 + r) * T + t) * F + f;
        if      (a == 0) xrow[j]  = x[idx];
        else if (a == 1) mrow[j]  = m[idx];
        else if (a == 2) drow[j]  = d[idx];
        else if (a == 3) txrow[j] = tx[idx];
        else             evrow[j] = tmask[idx];
      } else if (i < 1408) {
        const int j = i - 1280, r = j >> 6, k2 = j & 63;
        const int base = ((row0 + r) * T + t) * F;
        d2[j] = pack2(d[base + 2 * k2], d[base + 2 * k2 + 1]);
      } else if (i < 1536) {
        const int j = i - 1408, r = j >> 6, q = j & 63;
        const int base = ((row0 + r) * T + t) * F;
        gxm2[r * 128 + 64 + q] = pack2(m[base + 2 * q], m[base + 2 * q + 1]);
      } else {
        const int j = i - 1536, r = j >> 5, w = j & 31;   // m -> i8 (scale 15.875)
        const int base = ((row0 + r) * T + t) * F + 4 * w;
        const int q0 = __float2int_rn(m[base] * ACT_S);
        const int q1 = __float2int_rn(m[base + 1] * ACT_S);
        const int q2 = __float2int_rn(m[base + 2] * ACT_S);
        const int q3 = __float2int_rn(m[base + 3] * ACT_S);
        actq[r * 64 + 32 + w] =
            (q0 & 0xFF) | ((q1 & 0xFF) << 8) | ((q2 & 0xFF) << 16) | ((q3 & 0xFF) << 24);
      }
    }
    __syncthreads();

    // ---- C: gamma_h (K=64 f16 pairs), decay reg h, pack hq via shfl ----
    {
      float g0 = tdb, g1 = tdb;
#pragma unroll 8
      for (int k2 = 0; k2 < 64; ++k2) {
        const h2_t w = as_h2(wsu[OFF_TD2 + (k2 << 9) + tid]);
        g0 = fdot2(w, as_h2(d2[k2]), g0);
        g1 = fdot2(w, as_h2(d2[64 + k2]), g1);
      }
      h0 *= __expf(-fmaxf(g0, 0.f));
      h1 *= __expf(-fmaxf(g1, 0.f));
      int q0 = __float2int_rn(h0 * 127.f), q1 = __float2int_rn(h1 * 127.f);
      const int a1 = __shfl_down(q0, 1, 64), a2 = __shfl_down(q0, 2, 64), a3 = __shfl_down(q0, 3, 64);
      const int b1 = __shfl_down(q1, 1, 64), b2 = __shfl_down(q1, 2, 64), b3 = __shfl_down(q1, 3, 64);
      if ((tid & 3) == 0) {
        hq[tid >> 2] =
            (q0 & 0xFF) | ((a1 & 0xFF) << 8) | ((a2 & 0xFF) << 16) | ((a3 & 0xFF) << 24);
        hq[128 + (tid >> 2)] =
            (q1 & 0xFF) | ((b1 & 0xFF) << 8) | ((b2 & 0xFF) << 16) | ((b3 & 0xFF) << 24);
      }
    }
    __syncthreads();

    // ---- E: x_hist (i8 K=128 words), gamma_x, x_c, pack xc2/gx pairs ----
    if (tid < 256) {
      const int r = tid >> 7, f = tid & 127;
      int isum = 0;
#pragma unroll 8
      for (int k4 = 0; k4 < 128; ++k4)
        isum = sdot4((int)wsu[OFF_HISTQ + (k4 << 7) + f], hq[r * 128 + k4], isum);
      const float xh = fmaf((float)isum, fsch_f, hb);
      xh_ls[tid] = xh;
      const float gx = __expf(-fmaxf(fmaf(drow[tid], dxw, dxb), 0.f));
      const float mv = mrow[tid];
      const float xc = mv * xrow[tid] + (1.f - mv) * xh;
      xc_ls[tid] = xc;
      const float xcs = __shfl_down(xc, 1, 64);
      const float gxs = __shfl_down(gx, 1, 64);
      if (!(f & 1)) {
        xc2[r * 64 + (f >> 1)]   = pack2(xc, xcs);
        gxm2[r * 128 + (f >> 1)] = pack2(gx, gxs);
      }
    }
    __syncthreads();

    // ---- G: z_h, alpha, c_h, c_c, out, loss partials, pack cc -> i8 ----
    if (tid < 256) {
      const int r = tid >> 7, f = tid & 127;
      float z = fb;
#pragma unroll 8
      for (int k2 = 0; k2 < 64; ++k2)
        z = fdot2(as_h2(wsu[OFF_FEAT2 + (k2 << 7) + f]), as_h2(xc2[r * 64 + k2]), z);
      z -= xc_ls[tid] * fd;
      float aa = wb;
#pragma unroll 8
      for (int k2 = 0; k2 < 128; ++k2)
        aa = fdot2(as_h2(wsu[OFF_WC2 + (k2 << 7) + f]), as_h2(gxm2[r * 128 + k2]), aa);
      const float al = fast_sig(aa);
      const float xh = xh_ls[tid];
      const float ch = al * z + (1.f - al) * xh;
      const float mv = mrow[tid];
      const float cc = mv * xrow[tid] + (1.f - mv) * ch;
      out[((row0 + r) * T + t) * F + f] = cc;
      const float ev = evrow[tid], tg = txrow[tid];
      const float e1 = xh - tg, e2 = z - tg, e3 = ch - tg;
      const float s1 = wave_sum(ev * (e1 * e1 + e2 * e2 + e3 * e3));
      const float s2 = wave_sum(ev);
      if ((tid & 63) == 0) { redA[tid >> 6] = s1; redB[tid >> 6] = s2; }
      int qc = __float2int_rn(fminf(fmaxf(cc, -8.f), 8.f) * ACT_S);
      const int c1s = __shfl_down(qc, 1, 64), c2s = __shfl_down(qc, 2, 64), c3s = __shfl_down(qc, 3, 64);
      if (!(f & 3))
        actq[r * 64 + (f >> 2)] =
            (qc & 0xFF) | ((c1s & 0xFF) << 8) | ((c2s & 0xFF) << 16) | ((c3s & 0xFF) << 24);
    }
    __syncthreads();

    // ---- I: gates all-i8 (K=64 cc|m words + 128 h words), LSTM update ----
    {
      if (tid == 511) {
        atomicAdd(&num[t], redA[0] + redA[1] + redA[2] + redA[3]);
        atomicAdd(&den[t], redB[0] + redB[1] + redB[2] + redB[3]);
      }
      int ci0 = 0, cf0 = 0, cg0 = 0, co0 = 0, ci1 = 0, cf1 = 0, cg1 = 0, co1 = 0;
      const unsigned* wq = wsu + OFF_WQCC + 4 * tid;
#pragma unroll 8
      for (int k4 = 0; k4 < 64; ++k4) {
        const uint4 w = *(const uint4*)(wq + (k4 << 11));
        const int a0 = (int)actq[k4], a1 = (int)actq[64 + k4];
        ci0 = sdot4((int)w.x, a0, ci0); cf0 = sdot4((int)w.y, a0, cf0);
        cg0 = sdot4((int)w.z, a0, cg0); co0 = sdot4((int)w.w, a0, co0);
        ci1 = sdot4((int)w.x, a1, ci1); cf1 = sdot4((int)w.y, a1, cf1);
        cg1 = sdot4((int)w.z, a1, cg1); co1 = sdot4((int)w.w, a1, co1);
      }
      int hi0 = 0, hf0 = 0, hg0 = 0, ho0 = 0, hi1 = 0, hf1 = 0, hg1 = 0, ho1 = 0;
      const unsigned* wh = wsu + OFF_WQH + 4 * tid;
#pragma unroll 8
      for (int k4 = 0; k4 < 128; ++k4) {
        const uint4 w = *(const uint4*)(wh + (k4 << 11));
        const int a0 = hq[k4], a1 = hq[128 + k4];
        hi0 = sdot4((int)w.x, a0, hi0); hf0 = sdot4((int)w.y, a0, hf0);
        hg0 = sdot4((int)w.z, a0, hg0); ho0 = sdot4((int)w.w, a0, ho0);
        hi1 = sdot4((int)w.x, a1, hi1); hf1 = sdot4((int)w.y, a1, hf1);
        hg1 = sdot4((int)w.z, a1, hg1); ho1 = sdot4((int)w.w, a1, ho1);
      }
      {
        const float ai = bs.x + fscc4.x * (float)ci0 + fsch4.x * (float)hi0;
        const float af = bs.y + fscc4.y * (float)cf0 + fsch4.y * (float)hf0;
        const float ag = bs.z + fscc4.z * (float)cg0 + fsch4.z * (float)hg0;
        const float ao = bs.w + fscc4.w * (float)co0 + fsch4.w * (float)ho0;
        const float ig = fast_sig(ai), fg = fast_sig(af);
        const float gg = fast_tanh(ag), og = fast_sig(ao);
        c0 = fg * c0 + ig * gg;
        h0 = og * fast_tanh(c0);
      }
      {
        const float ai = bs.x + fscc4.x * (float)ci1 + fsch4.x * (float)hi1;
        const float af = bs.y + fscc4.y * (float)cf1 + fsch4.y * (float)hf1;
        const float ag = bs.z + fscc4.z * (float)cg1 + fsch4.z * (float)hg1;
        const float ao = bs.w + fscc4.w * (float)co1 + fsch4.w * (float)ho1;
        const float ig = fast_sig(ai), fg = fast_sig(af);
        const float gg = fast_tanh(ag), og = fast_sig(ao);
        c1 = fg * c1 + ig * gg;
        h1 = og * fast_tanh(c1);
      }
    }
    __syncthreads();   // protect actq/hq/rows from next step's writers
  }
}

__global__ void finalize(const float* __restrict__ num, const float* __restrict__ den,
                         float* __restrict__ out) {
  __shared__ float red[2];
  const int t = threadIdx.x;     // 128 threads
  float v = num[t] / (den[t] + 1e-8f);
  v = wave_sum(v);
  if ((t & 63) == 0) red[t >> 6] = v;
  __syncthreads();
  if (t == 0) out[(size_t)B * T * F] = (red[0] + red[1]) / (float)T;
}

extern "C" void kernel_launch(void* const* d_in, const int* in_sizes, int n_in,
                              void* d_out, int out_size, void* d_ws, size_t ws_size,
                              hipStream_t stream) {
  const float* x      = (const float*)d_in[0];
  const float* m      = (const float*)d_in[1];
  const float* d      = (const float*)d_in[2];
  const float* tx     = (const float*)d_in[3];
  const float* tmask  = (const float*)d_in[4];
  const float* td_h_W = (const float*)d_in[5];
  const float* td_h_b = (const float*)d_in[6];
  const float* td_x_W = (const float*)d_in[7];
  const float* td_x_b = (const float*)d_in[8];
  const float* hist_W = (const float*)d_in[9];
  const float* hist_b = (const float*)d_in[10];
  const float* feat_W = (const float*)d_in[11];
  const float* feat_b = (const float*)d_in[12];
  const float* wc_W   = (const float*)d_in[13];
  const float* wc_b   = (const float*)d_in[14];
  const float* W_ih   = (const float*)d_in[15];
  const float* W_hh   = (const float*)d_in[16];
  const float* b_ih   = (const float*)d_in[17];
  const float* b_hh   = (const float*)d_in[18];

  float*    wsf = (float*)d_ws;
  unsigned* wsu = (unsigned*)d_ws;
  float*    out = (float*)d_out;

  if (ws_size < WS_WORDS * 4) return;   // OOB tripwire

  hipMemsetAsync(d_ws, 0, 256 * sizeof(float), stream);   // num/den
  prep_f16<<<dim3((59520 + 255) / 256), dim3(256), 0, stream>>>(
      td_h_W, feat_W, wc_W, b_ih, b_hh, wsu, wsf);
  prep_quant_wih<<<dim3(2048), dim3(64), 0, stream>>>(
      W_ih, wsu + OFF_WQCC, wsf + OFF_FSCC);
  prep_quant_whh<<<dim3(2048), dim3(128), 0, stream>>>(
      W_hh, wsu + OFF_WQH, wsf + OFF_FSCHG);
  prep_quant_hist<<<dim3(128), dim3(128), 0, stream>>>(
      hist_W, wsu + OFF_HISTQ, wsf + OFF_FSCH);
  rits_batch<<<dim3(NBLK), dim3(512), 0, stream>>>(
      x, m, d, tx, tmask, td_h_b, td_x_W, td_x_b, hist_b, feat_b, wc_b,
      wsu, wsf, wsf + OFF_NUM, wsf + OFF_DEN, out);
  finalize<<<dim3(1), dim3(128), 0, stream>>>(wsf + OFF_NUM, wsf + OFF_DEN, out);
}

// Round 7
// 2432.694 us; speedup vs baseline: 2.5086x; 1.7471x over previous
//
#include <hip/hip_runtime.h>

#define DEVINL __device__ __forceinline__

namespace {
constexpr int B = 256, T = 128, F = 128, H = 512;
constexpr int NBLK = 256;        // 1 batch row per block, all 256 CUs active
constexpr int NTHR = 1024;       // 16 waves: latency hiding at 4 waves/SIMD

// workspace layout in 4-byte words (identical to round 6)
constexpr size_t OFF_NUM    = 0;                         // [128] loss numerators
constexpr size_t OFF_DEN    = 128;                       // [128] denominators
constexpr size_t OFF_WQCC   = 256;                       // gates cc|m i8x4 [64 k4][2048 col]
constexpr size_t OFF_WQH    = OFF_WQCC + 64 * 2048;      // gates h    i8x4 [128 k4][2048 col]
constexpr size_t OFF_FSCC   = OFF_WQH + 128 * 2048;      // [2048] colmax/(127*15.875)
constexpr size_t OFF_FSCHG  = OFF_FSCC + 2048;           // [2048] colmax/16129
constexpr size_t OFF_HISTQ  = OFF_FSCHG + 2048;          // hist i8x4 [128 k4][128 f]
constexpr size_t OFF_FSCH   = OFF_HISTQ + 128 * 128;     // [128] colmax/16129
constexpr size_t OFF_TD2    = OFF_FSCH + 128;            // td_h f16x2 [64 k2][512 j]
constexpr size_t OFF_FEAT2  = OFF_TD2 + 64 * 512;        // feat f16x2 [64 k2][128 f]
constexpr size_t OFF_WC2    = OFF_FEAT2 + 64 * 128;      // wc   f16x2 [128 k2][128 f]
constexpr size_t OFF_BSUM   = OFF_WC2 + 128 * 128;       // [2048] b_ih+b_hh gate-interleaved
constexpr size_t OFF_FDIAG  = OFF_BSUM + 2048;           // [128] f16-rounded feat diag
constexpr size_t WS_WORDS   = OFF_FDIAG + 128;           // ~1.81 MB

constexpr float ACT_S  = 15.875f;                // cc|m activation scale (clamp +-8)
constexpr float DEQ_CC = 1.f / (127.f * 15.875f);
constexpr float DEQ_H  = 1.f / (127.f * 127.f);
}

typedef _Float16 h2_t __attribute__((ext_vector_type(2)));

DEVINL h2_t as_h2(unsigned u) { union { unsigned u; h2_t h; } c; c.u = u; return c.h; }
DEVINL unsigned pack2(float a, float b) {
  union { h2_t h; unsigned u; } c;
  c.h = h2_t{(_Float16)a, (_Float16)b};
  return c.u;
}

#if defined(__has_builtin)
#if __has_builtin(__builtin_amdgcn_fdot2)
#define HAVE_FDOT2 1
#endif
#if __has_builtin(__builtin_amdgcn_sdot4)
#define HAVE_SDOT4 1
#endif
#endif
#ifdef HAVE_FDOT2
DEVINL float fdot2(h2_t a, h2_t b, float c) { return __builtin_amdgcn_fdot2(a, b, c, false); }
#else
DEVINL float fdot2(h2_t a, h2_t b, float c) {
  return fmaf((float)a.x, (float)b.x, fmaf((float)a.y, (float)b.y, c));
}
#endif
#ifdef HAVE_SDOT4
DEVINL int sdot4(int a, int b, int c) { return __builtin_amdgcn_sdot4(a, b, c, false); }
#else
DEVINL int sdot4(int a, int b, int c) {
  return c + ((a << 24) >> 24) * ((b << 24) >> 24)
           + ((a << 16) >> 24) * ((b << 16) >> 24)
           + ((a << 8) >> 24) * ((b << 8) >> 24)
           + (a >> 24) * (b >> 24);
}
#endif

DEVINL float fast_sig(float x)  { return 1.f / (1.f + __expf(-x)); }
DEVINL float fast_tanh(float x) { return 1.f - 2.f / (1.f + __expf(2.f * x)); }

DEVINL float wave_sum(float v) {
#pragma unroll
  for (int s = 32; s; s >>= 1) v += __shfl_down(v, s, 64);
  return v;
}
DEVINL float wave_max(float v) {
#pragma unroll
  for (int s = 32; s; s >>= 1) v = fmaxf(v, __shfl_down(v, s, 64));
  return v;
}

// ---- prep: f16 tables + biases (TD2, FEAT2, WC2, BSUM, FDIAG) ----
__global__ void prep_f16(const float* __restrict__ td_h_W, const float* __restrict__ feat_W,
                         const float* __restrict__ wc_W, const float* __restrict__ b_ih,
                         const float* __restrict__ b_hh,
                         unsigned* __restrict__ wsu, float* __restrict__ wsf) {
  int idx = blockIdx.x * blockDim.x + threadIdx.x;
  if (idx < 32768) {                           // TD2 [64][512]
    const int k2 = idx >> 9, j = idx & 511;
    wsu[OFF_TD2 + idx] = pack2(td_h_W[j * 128 + 2 * k2], td_h_W[j * 128 + 2 * k2 + 1]);
  } else if (idx < 40960) {                    // FEAT2 [64][128]
    const int i = idx - 32768, k2 = i >> 7, f = i & 127;
    wsu[OFF_FEAT2 + i] = pack2(feat_W[f * 128 + 2 * k2], feat_W[f * 128 + 2 * k2 + 1]);
  } else if (idx < 57344) {                    // WC2 [128][128]
    const int i = idx - 40960, k2 = i >> 7, f = i & 127;
    wsu[OFF_WC2 + i] = pack2(wc_W[f * 256 + 2 * k2], wc_W[f * 256 + 2 * k2 + 1]);
  } else if (idx < 59392) {                    // BSUM [2048]
    const int i = idx - 57344, unit = i >> 2, g = i & 3;
    wsf[OFF_BSUM + i] = b_ih[g * 512 + unit] + b_hh[g * 512 + unit];
  } else if (idx < 59520) {                    // FDIAG [128]
    const int f = idx - 59392;
    wsf[OFF_FDIAG + f] = (float)(_Float16)feat_W[f * 129];
  }
}

// ---- prep: i8 quant of W_ih columns (K=256, cc|m part), per-column scale ----
__global__ void prep_quant_wih(const float* __restrict__ Wih,
                               unsigned* __restrict__ wq, float* __restrict__ fscc) {
  const int col = blockIdx.x;                  // 2048 = 4*unit+gate
  const int unit = col >> 2, g = col & 3;
  const float* src = Wih + (size_t)(g * 512 + unit) * 256;
  const int t = threadIdx.x;                   // 64 threads (one wave), 4 k each
  const float4 v = ((const float4*)src)[t];
  float mx = fmaxf(fmaxf(fabsf(v.x), fabsf(v.y)), fmaxf(fabsf(v.z), fabsf(v.w)));
  mx = wave_max(mx);
  mx = __shfl(mx, 0, 64);
  const float s = (mx > 0.f) ? 127.f / mx : 0.f;
  const int q0 = __float2int_rn(v.x * s), q1 = __float2int_rn(v.y * s);
  const int q2 = __float2int_rn(v.z * s), q3 = __float2int_rn(v.w * s);
  wq[t * 2048 + col] =
      (q0 & 0xFF) | ((q1 & 0xFF) << 8) | ((q2 & 0xFF) << 16) | ((q3 & 0xFF) << 24);
  if (t == 0) fscc[col] = mx * DEQ_CC;
}

// ---- prep: i8 quant of W_hh columns (K=512, h part) ----
__global__ void prep_quant_whh(const float* __restrict__ Whh,
                               unsigned* __restrict__ wq, float* __restrict__ fschg) {
  const int col = blockIdx.x;
  const int unit = col >> 2, g = col & 3;
  const float* src = Whh + (size_t)(g * 512 + unit) * 512;
  const int t = threadIdx.x;                   // 128 threads, 4 k each
  const float4 v = ((const float4*)src)[t];
  float mx = fmaxf(fmaxf(fabsf(v.x), fabsf(v.y)), fmaxf(fabsf(v.z), fabsf(v.w)));
  mx = wave_max(mx);
  __shared__ float wm[2];
  if ((t & 63) == 0) wm[t >> 6] = mx;
  __syncthreads();
  const float maxv = fmaxf(wm[0], wm[1]);
  const float s = (maxv > 0.f) ? 127.f / maxv : 0.f;
  const int q0 = __float2int_rn(v.x * s), q1 = __float2int_rn(v.y * s);
  const int q2 = __float2int_rn(v.z * s), q3 = __float2int_rn(v.w * s);
  wq[t * 2048 + col] =
      (q0 & 0xFF) | ((q1 & 0xFF) << 8) | ((q2 & 0xFF) << 16) | ((q3 & 0xFF) << 24);
  if (t == 0) fschg[col] = maxv * DEQ_H;
}

// ---- prep: i8 quant of hist_W rows (K=512) ----
__global__ void prep_quant_hist(const float* __restrict__ histW,
                                unsigned* __restrict__ histq, float* __restrict__ fsch) {
  const int f = blockIdx.x;                    // 128
  const float* src = histW + (size_t)f * 512;
  const int t = threadIdx.x;                   // 128 threads
  const float4 v = ((const float4*)src)[t];
  float mx = fmaxf(fmaxf(fabsf(v.x), fabsf(v.y)), fmaxf(fabsf(v.z), fabsf(v.w)));
  mx = wave_max(mx);
  __shared__ float wm[2];
  if ((t & 63) == 0) wm[t >> 6] = mx;
  __syncthreads();
  const float maxv = fmaxf(wm[0], wm[1]);
  const float s = (maxv > 0.f) ? 127.f / maxv : 0.f;
  const int q0 = __float2int_rn(v.x * s), q1 = __float2int_rn(v.y * s);
  const int q2 = __float2int_rn(v.z * s), q3 = __float2int_rn(v.w * s);
  histq[t * 128 + f] =
      (q0 & 0xFF) | ((q1 & 0xFF) << 8) | ((q2 & 0xFF) << 16) | ((q3 & 0xFF) << 24);
  if (t == 0) fsch[f] = maxv * DEQ_H;
}

// ---- main: 256 blocks x 1024 threads; 1 row/block; K-split partials;
//      h,c in registers of thread=unit (tid<512); weights i8/f16 from L2 ----
__global__ void __launch_bounds__(1024) rits_batch(
    const float* __restrict__ x, const float* __restrict__ m, const float* __restrict__ d,
    const float* __restrict__ tx, const float* __restrict__ tmask,
    const float* __restrict__ td_h_b, const float* __restrict__ td_x_W,
    const float* __restrict__ td_x_b, const float* __restrict__ hist_b,
    const float* __restrict__ feat_b, const float* __restrict__ wc_b,
    const unsigned* __restrict__ wsu, const float* __restrict__ wsf,
    float* __restrict__ num, float* __restrict__ den, float* __restrict__ out)
{
  const int tid = threadIdx.x;
  const int row = blockIdx.x;
  const int unit = tid & 511;                  // phase C/I unit
  const int kh = tid >> 9;                     // phase I k-half

  __shared__ unsigned actq[64];                // cc i8 words 0..31 | m i8 32..63
  __shared__ int hq[128];                      // decayed h i8 (scale 127)
  __shared__ unsigned d2[64];                  // d f16 pairs
  __shared__ unsigned xc2[64];                 // x_c f16 pairs
  __shared__ unsigned gxm2[128];               // gx pairs 0..63 | m pairs 64..127
  __shared__ float xrow[128], mrow[128], drow[128], txrow[128], evrow[128];
  __shared__ int   partI[1024];                // x_hist K-split partials
  __shared__ float partZ[1024], partA[1024];   // feat / alpha partials
  __shared__ int4  partHc[512], partHh[512];   // gates partials (upper k-half)
  __shared__ float redA[2], redB[2];

  // persistent per-thread constants
  const float4 bs    = *(const float4*)(wsf + OFF_BSUM + 4 * unit);
  const float4 fscc4 = *(const float4*)(wsf + OFF_FSCC + 4 * unit);
  const float4 fsch4 = *(const float4*)(wsf + OFF_FSCHG + 4 * unit);
  const float tdb = td_h_b[unit];
  const int fc = tid & 127;
  const float hb = hist_b[fc], fb = feat_b[fc], wb = wc_b[fc];
  const float fd = wsf[OFF_FDIAG + fc];
  const float dxw = td_x_W[fc * 129], dxb = td_x_b[fc];
  const float fsch_f = wsf[OFF_FSCH + fc];

  float h0 = 0.f, c0 = 0.f;                    // recurrent state (tid<512)

  for (int t = 0; t < T; ++t) {
    const int base = (row * T + t) * F;
    float xh_r = 0.f, xc_r = 0.f;              // live E' -> G' (tid<128)

    // ---- A: stage this step's input row (800 items, <=1 per thread) ----
    if (tid < 640) {
      const int a = tid >> 7, f = tid & 127;
      const float v = (a == 0 ? x[base + f] : a == 1 ? m[base + f] : a == 2 ? d[base + f]
                       : a == 3 ? tx[base + f] : tmask[base + f]);
      if      (a == 0) xrow[f]  = v;
      else if (a == 1) mrow[f]  = v;
      else if (a == 2) drow[f]  = v;
      else if (a == 3) txrow[f] = v;
      else             evrow[f] = v;
    } else if (tid < 704) {
      const int k2 = tid - 640;
      d2[k2] = pack2(d[base + 2 * k2], d[base + 2 * k2 + 1]);
    } else if (tid < 768) {
      const int q = tid - 704;
      gxm2[64 + q] = pack2(m[base + 2 * q], m[base + 2 * q + 1]);
    } else if (tid < 800) {
      const int w = tid - 768;
      const int b4 = base + 4 * w;
      const int q0 = __float2int_rn(m[b4] * ACT_S);
      const int q1 = __float2int_rn(m[b4 + 1] * ACT_S);
      const int q2 = __float2int_rn(m[b4 + 2] * ACT_S);
      const int q3 = __float2int_rn(m[b4 + 3] * ACT_S);
      actq[32 + w] =
          (q0 & 0xFF) | ((q1 & 0xFF) << 8) | ((q2 & 0xFF) << 16) | ((q3 & 0xFF) << 24);
    }
    __syncthreads();

    // ---- C: gamma_h (K=64 f16 pairs), decay reg h, pack hq via shfl ----
    if (tid < 512) {
      float g0 = tdb;
#pragma unroll 8
      for (int k2 = 0; k2 < 64; ++k2)
        g0 = fdot2(as_h2(wsu[OFF_TD2 + (k2 << 9) + tid]), as_h2(d2[k2]), g0);
      h0 *= __expf(-fmaxf(g0, 0.f));
      int q = __float2int_rn(h0 * 127.f);
      const int a1 = __shfl_down(q, 1, 64), a2 = __shfl_down(q, 2, 64), a3 = __shfl_down(q, 3, 64);
      if ((tid & 3) == 0)
        hq[tid >> 2] =
            (q & 0xFF) | ((a1 & 0xFF) << 8) | ((a2 & 0xFF) << 16) | ((a3 & 0xFF) << 24);
    }
    __syncthreads();

    // ---- E: x_hist partials (i8, K split 8 ways over all 16 waves) ----
    {
      const int kq = tid >> 7;
      int isum = 0;
#pragma unroll 8
      for (int k = 0; k < 16; ++k) {
        const int k4 = kq * 16 + k;
        isum = sdot4((int)wsu[OFF_HISTQ + (k4 << 7) + fc], hq[k4], isum);
      }
      partI[tid] = isum;
    }
    __syncthreads();

    // ---- E': reduce x_hist; gamma_x; x_c; pack xc2/gx pairs ----
    if (tid < 128) {
      int isum = 0;
#pragma unroll
      for (int i = 0; i < 8; ++i) isum += partI[tid + 128 * i];
      xh_r = fmaf((float)isum, fsch_f, hb);
      const float gx = __expf(-fmaxf(fmaf(drow[tid], dxw, dxb), 0.f));
      const float mv = mrow[tid];
      xc_r = mv * xrow[tid] + (1.f - mv) * xh_r;
      const float xcs = __shfl_down(xc_r, 1, 64);
      const float gxs = __shfl_down(gx, 1, 64);
      if (!(tid & 1)) {
        xc2[tid >> 1]  = pack2(xc_r, xcs);
        gxm2[tid >> 1] = pack2(gx, gxs);
      }
    }
    __syncthreads();

    // ---- G: feat + alpha partials (f16, K split 8 ways) ----
    {
      const int kq = tid >> 7;
      float zs = 0.f;
#pragma unroll 8
      for (int k = 0; k < 8; ++k) {
        const int k2 = kq * 8 + k;
        zs = fdot2(as_h2(wsu[OFF_FEAT2 + (k2 << 7) + fc]), as_h2(xc2[k2]), zs);
      }
      partZ[tid] = zs;
      float as = 0.f;
#pragma unroll 8
      for (int k = 0; k < 16; ++k) {
        const int k2 = kq * 16 + k;
        as = fdot2(as_h2(wsu[OFF_WC2 + (k2 << 7) + fc]), as_h2(gxm2[k2]), as);
      }
      partA[tid] = as;
    }
    __syncthreads();

    // ---- G': z_h, alpha, c_h, c_c, out, loss partials, pack cc -> i8 ----
    if (tid < 128) {
      float z = fb, aa = wb;
#pragma unroll
      for (int i = 0; i < 8; ++i) { z += partZ[tid + 128 * i]; aa += partA[tid + 128 * i]; }
      z -= xc_r * fd;                          // remove diagonal
      const float al = fast_sig(aa);
      const float ch = al * z + (1.f - al) * xh_r;
      const float mv = mrow[tid];
      const float cc = mv * xrow[tid] + (1.f - mv) * ch;
      out[base + tid] = cc;
      const float ev = evrow[tid], tg = txrow[tid];
      const float e1 = xh_r - tg, e2 = z - tg, e3 = ch - tg;
      const float s1 = wave_sum(ev * (e1 * e1 + e2 * e2 + e3 * e3));
      const float s2 = wave_sum(ev);
      if ((tid & 63) == 0) { redA[tid >> 6] = s1; redB[tid >> 6] = s2; }
      int qc = __float2int_rn(fminf(fmaxf(cc, -8.f), 8.f) * ACT_S);
      const int c1s = __shfl_down(qc, 1, 64), c2s = __shfl_down(qc, 2, 64), c3s = __shfl_down(qc, 3, 64);
      if (!(tid & 3))
        actq[tid >> 2] =
            (qc & 0xFF) | ((c1s & 0xFF) << 8) | ((c2s & 0xFF) << 16) | ((c3s & 0xFF) << 24);
    }
    __syncthreads();

    // ---- I: gates partials, K split 2 ways (8 dots per 16B load kept) ----
    {
      if (tid == 1023) {
        atomicAdd(&num[t], redA[0] + redA[1]);
        atomicAdd(&den[t], redB[0] + redB[1]);
      }
      int ci = 0, cf = 0, cg = 0, co = 0;
      const unsigned* wq = wsu + OFF_WQCC + 4 * unit;
#pragma unroll 8
      for (int k = 0; k < 32; ++k) {
        const int k4 = kh * 32 + k;
        const uint4 w = *(const uint4*)(wq + (k4 << 11));
        const int a0 = (int)actq[k4];
        ci = sdot4((int)w.x, a0, ci); cf = sdot4((int)w.y, a0, cf);
        cg = sdot4((int)w.z, a0, cg); co = sdot4((int)w.w, a0, co);
      }
      int hi = 0, hf = 0, hg = 0, ho = 0;
      const unsigned* wh = wsu + OFF_WQH + 4 * unit;
#pragma unroll 8
      for (int k = 0; k < 64; ++k) {
        const int k4 = kh * 64 + k;
        const uint4 w = *(const uint4*)(wh + (k4 << 11));
        const int a0 = hq[k4];
        hi = sdot4((int)w.x, a0, hi); hf = sdot4((int)w.y, a0, hf);
        hg = sdot4((int)w.z, a0, hg); ho = sdot4((int)w.w, a0, ho);
      }
      if (tid >= 512) {
        partHc[unit] = int4{ci, cf, cg, co};
        partHh[unit] = int4{hi, hf, hg, ho};
      }
      __syncthreads();
      if (tid < 512) {
        const int4 pc = partHc[unit], ph = partHh[unit];
        const float ai = bs.x + fscc4.x * (float)(ci + pc.x) + fsch4.x * (float)(hi + ph.x);
        const float af = bs.y + fscc4.y * (float)(cf + pc.y) + fsch4.y * (float)(hf + ph.y);
        const float ag = bs.z + fscc4.z * (float)(cg + pc.z) + fsch4.z * (float)(hg + ph.z);
        const float ao = bs.w + fscc4.w * (float)(co + pc.w) + fsch4.w * (float)(ho + ph.w);
        const float ig = fast_sig(ai), fg = fast_sig(af);
        const float gg = fast_tanh(ag), og = fast_sig(ao);
        c0 = fg * c0 + ig * gg;
        h0 = og * fast_tanh(c0);
      }
    }
    __syncthreads();   // protect actq/hq/rows/partials from next step's writers
  }
}

__global__ void finalize(const float* __restrict__ num, const float* __restrict__ den,
                         float* __restrict__ out) {
  __shared__ float red[2];
  const int t = threadIdx.x;     // 128 threads
  float v = num[t] / (den[t] + 1e-8f);
  v = wave_sum(v);
  if ((t & 63) == 0) red[t >> 6] = v;
  __syncthreads();
  if (t == 0) out[(size_t)B * T * F] = (red[0] + red[1]) / (float)T;
}

extern "C" void kernel_launch(void* const* d_in, const int* in_sizes, int n_in,
                              void* d_out, int out_size, void* d_ws, size_t ws_size,
                              hipStream_t stream) {
  const float* x      = (const float*)d_in[0];
  const float* m      = (const float*)d_in[1];
  const float* d      = (const float*)d_in[2];
  const float* tx     = (const float*)d_in[3];
  const float* tmask  = (const float*)d_in[4];
  const float* td_h_W = (const float*)d_in[5];
  const float* td_h_b = (const float*)d_in[6];
  const float* td_x_W = (const float*)d_in[7];
  const float* td_x_b = (const float*)d_in[8];
  const float* hist_W = (const float*)d_in[9];
  const float* hist_b = (const float*)d_in[10];
  const float* feat_W = (const float*)d_in[11];
  const float* feat_b = (const float*)d_in[12];
  const float* wc_W   = (const float*)d_in[13];
  const float* wc_b   = (const float*)d_in[14];
  const float* W_ih   = (const float*)d_in[15];
  const float* W_hh   = (const float*)d_in[16];
  const float* b_ih   = (const float*)d_in[17];
  const float* b_hh   = (const float*)d_in[18];

  float*    wsf = (float*)d_ws;
  unsigned* wsu = (unsigned*)d_ws;
  float*    out = (float*)d_out;

  if (ws_size < WS_WORDS * 4) return;   // OOB tripwire

  hipMemsetAsync(d_ws, 0, 256 * sizeof(float), stream);   // num/den
  prep_f16<<<dim3((59520 + 255) / 256), dim3(256), 0, stream>>>(
      td_h_W, feat_W, wc_W, b_ih, b_hh, wsu, wsf);
  prep_quant_wih<<<dim3(2048), dim3(64), 0, stream>>>(
      W_ih, wsu + OFF_WQCC, wsf + OFF_FSCC);
  prep_quant_whh<<<dim3(2048), dim3(128), 0, stream>>>(
      W_hh, wsu + OFF_WQH, wsf + OFF_FSCHG);
  prep_quant_hist<<<dim3(128), dim3(128), 0, stream>>>(
      hist_W, wsu + OFF_HISTQ, wsf + OFF_FSCH);
  rits_batch<<<dim3(NBLK), dim3(NTHR), 0, stream>>>(
      x, m, d, tx, tmask, td_h_b, td_x_W, td_x_b, hist_b, feat_b, wc_b,
      wsu, wsf, wsf + OFF_NUM, wsf + OFF_DEN, out);
  finalize<<<dim3(1), dim3(128), 0, stream>>>(wsf + OFF_NUM, wsf + OFF_DEN, out);
}